// Round 1
// baseline (202.851 us; speedup 1.0000x reference)
//
#include <hip/hip_runtime.h>

#define LOG_CLAMP -100.0f

// ws layout: ws[0] = S1 (sum over gt==1 of -max(log x, -100))
//            ws[1] = S0 (sum over gt==0 of -max(log1p(-x), -100))
//            ws[2] = s  (count of gt==1, accumulated as double)

__global__ __launch_bounds__(256) void bce_reduce_kernel(
    const float* __restrict__ x, const int* __restrict__ gt,
    int n, double* __restrict__ ws) {
  float s1 = 0.0f, s0 = 0.0f;
  float cnt = 0.0f;

  const int tid = blockIdx.x * blockDim.x + threadIdx.x;
  const int stride = gridDim.x * blockDim.x;

  const int n4 = n >> 2;
  const float4* __restrict__ x4 = reinterpret_cast<const float4*>(x);
  const int4* __restrict__ g4 = reinterpret_cast<const int4*>(gt);

  for (int i = tid; i < n4; i += stride) {
    float4 xv = x4[i];
    int4 gv = g4[i];

    // element 0
    if (gv.x != 0) { s1 -= fmaxf(logf(xv.x), LOG_CLAMP); cnt += 1.0f; }
    else           { s0 -= fmaxf(log1pf(-xv.x), LOG_CLAMP); }
    // element 1
    if (gv.y != 0) { s1 -= fmaxf(logf(xv.y), LOG_CLAMP); cnt += 1.0f; }
    else           { s0 -= fmaxf(log1pf(-xv.y), LOG_CLAMP); }
    // element 2
    if (gv.z != 0) { s1 -= fmaxf(logf(xv.z), LOG_CLAMP); cnt += 1.0f; }
    else           { s0 -= fmaxf(log1pf(-xv.z), LOG_CLAMP); }
    // element 3
    if (gv.w != 0) { s1 -= fmaxf(logf(xv.w), LOG_CLAMP); cnt += 1.0f; }
    else           { s0 -= fmaxf(log1pf(-xv.w), LOG_CLAMP); }
  }

  // tail (n not divisible by 4)
  for (int i = (n4 << 2) + tid; i < n; i += stride) {
    float xv = x[i];
    int gv = gt[i];
    if (gv != 0) { s1 -= fmaxf(logf(xv), LOG_CLAMP); cnt += 1.0f; }
    else         { s0 -= fmaxf(log1pf(-xv), LOG_CLAMP); }
  }

  // wave-level reduction (64 lanes)
  for (int off = 32; off > 0; off >>= 1) {
    s1  += __shfl_down(s1, off, 64);
    s0  += __shfl_down(s0, off, 64);
    cnt += __shfl_down(cnt, off, 64);
  }

  // cross-wave reduction via LDS (256 threads = 4 waves)
  __shared__ float red[3][4];
  const int lane = threadIdx.x & 63;
  const int wave = threadIdx.x >> 6;
  if (lane == 0) {
    red[0][wave] = s1;
    red[1][wave] = s0;
    red[2][wave] = cnt;
  }
  __syncthreads();
  if (threadIdx.x == 0) {
    float bs1 = red[0][0] + red[0][1] + red[0][2] + red[0][3];
    float bs0 = red[1][0] + red[1][1] + red[1][2] + red[1][3];
    float bc  = red[2][0] + red[2][1] + red[2][2] + red[2][3];
    atomicAdd(&ws[0], (double)bs1);
    atomicAdd(&ws[1], (double)bs0);
    atomicAdd(&ws[2], (double)bc);
  }
}

__global__ void bce_finalize_kernel(const double* __restrict__ ws,
                                    float* __restrict__ out, double n) {
  double S1 = ws[0];
  double S0 = ws[1];
  double s  = ws[2];
  // result = S1/(2s) + S0/(2(n-s))
  double res = S1 / (2.0 * s) + S0 / (2.0 * (n - s));
  out[0] = (float)res;
}

extern "C" void kernel_launch(void* const* d_in, const int* in_sizes, int n_in,
                              void* d_out, int out_size, void* d_ws, size_t ws_size,
                              hipStream_t stream) {
  const float* x = (const float*)d_in[0];
  const int* gt = (const int*)d_in[1];
  float* out = (float*)d_out;
  int n = in_sizes[0];

  double* ws = (double*)d_ws;
  // d_ws is re-poisoned to 0xAA before every launch — zero our accumulators.
  hipMemsetAsync(ws, 0, 3 * sizeof(double), stream);

  const int block = 256;
  const int grid = 2048;  // 256 CUs x 8 blocks/CU; grid-stride covers the rest
  bce_reduce_kernel<<<grid, block, 0, stream>>>(x, gt, n, ws);
  bce_finalize_kernel<<<1, 1, 0, stream>>>(ws, out, (double)n);
}